// Round 1
// baseline (29032.364 us; speedup 1.0000x reference)
//
#include <hip/hip_runtime.h>
#include <cstdint>
#include <cstddef>

#define H 1024
#define LSEQ 512
#define NB 256
#define INP 6
#define G4 4096

typedef unsigned short u16;
typedef __bf16 bf16;
typedef bf16 bf16x8 __attribute__((ext_vector_type(8)));
typedef float f32x4 __attribute__((ext_vector_type(4)));

static __device__ __forceinline__ u16 f2bf(float f) {
    uint32_t u = __builtin_bit_cast(uint32_t, f);
    uint32_t r = (u + 0x7FFFu + ((u >> 16) & 1u)) >> 16;
    return (u16)r;
}
static __device__ __forceinline__ float bf2f(u16 b) {
    return __builtin_bit_cast(float, ((uint32_t)b) << 16);
}
static __device__ __forceinline__ float sigm(float x) {
    return 1.0f / (1.0f + __expf(-x));
}
static __device__ __forceinline__ float tanh_fast(float x) {
    x = fminf(fmaxf(x, -30.f), 30.f);
    float t = __expf(-2.0f * x);
    return (1.0f - t) / (1.0f + t);
}

// ---- prep kernels -------------------------------------------------------
__global__ void pack_hi_lo(const float* __restrict__ src, u16* __restrict__ hi,
                           u16* __restrict__ lo, int n) {
    int i = blockIdx.x * blockDim.x + threadIdx.x;
    if (i >= n) return;
    float w = src[i];
    u16 h = f2bf(w);
    hi[i] = h;
    lo[i] = f2bf(w - bf2f(h));
}

__global__ void pack_cat(const float* __restrict__ Wih, const float* __restrict__ Whh,
                         u16* __restrict__ hi, u16* __restrict__ lo) {
    int i = blockIdx.x * blockDim.x + threadIdx.x;   // over 4096*2048
    int g = i >> 11, c = i & 2047;
    float w = (c < H) ? Wih[g * H + c] : Whh[g * H + (c - H)];
    u16 h = f2bf(w);
    hi[i] = h;
    lo[i] = f2bf(w - bf2f(h));
}

__global__ void bias_sum(const float* a0, const float* b0_, float* o0,
                         const float* a1, const float* b1_, float* o1) {
    int i = blockIdx.x * blockDim.x + threadIdx.x;
    if (i < G4) { o0[i] = a0[i] + b0_[i]; o1[i] = a1[i] + b1_[i]; }
}

// ---- fused LSTM step: gates = [A0|A1] @ W^T (+x@Wx^T) + bias; c,h update --
// Split-bf16 (hi/lo) 3-product MFMA for ~fp32 precision.
// Block: 256 thr (4 waves). Tile: BM=64 (wave m=16), BN=64 = 4 gates x 16 h-cols.
// B staged in LDS, row stride 144 B (+16 pad -> <=2-way bank aliasing, free).
// A frags read straight from global (L2-resident h buffers).
template<bool USE_X>
__global__ __launch_bounds__(256)
void lstm_step(const u16* __restrict__ A0h, const u16* __restrict__ A0l,
               const u16* __restrict__ A1h, const u16* __restrict__ A1l,
               int K0, int nstages,
               const u16* __restrict__ Wh, const u16* __restrict__ Wl, int strideW,
               const float* __restrict__ bias,
               const float* __restrict__ xt, const float* __restrict__ Wx,
               float* __restrict__ cbuf,
               u16* __restrict__ Hh, u16* __restrict__ Hl, int outcol)
{
    __shared__ uint4 ldsB4[18432 / 16];   // hi: rows 0..63 (144 B stride), lo at +9216
    __shared__ float ldsX[64][INP];
    __shared__ float ldsW6[64][INP];
    char* ldsB = (char*)ldsB4;

    const int tid  = threadIdx.x;
    const int lane = tid & 63;
    const int wav  = tid >> 6;
    const int quad = lane >> 4;
    const int jloc = lane & 15;
    const int j0 = (blockIdx.x & 63) << 4;   // h-col block (16 cols)
    const int m0 = (blockIdx.x >> 6) << 6;   // batch block (64 rows)

    if (USE_X) {
        if (tid < 64) {
            #pragma unroll
            for (int i = 0; i < INP; ++i) ldsX[tid][i] = xt[(m0 + tid) * INP + i];
        } else if (tid < 128) {
            int idx = tid - 64;
            int R = ((idx >> 4) << 10) + j0 + (idx & 15);
            #pragma unroll
            for (int i = 0; i < INP; ++i) ldsW6[idx][i] = Wx[R * INP + i];
        }
    }

    f32x4 acc[4];
    #pragma unroll
    for (int g = 0; g < 4; ++g) acc[g] = (f32x4){0.f, 0.f, 0.f, 0.f};

    // A fragment address: row m = lane&15 within wave's 16-row m-tile, k span quad*8
    const int rowA = m0 + (wav << 4) + jloc;
    const size_t aoff = (size_t)rowA * 2048 + quad * 8;

    // B staging: thread -> (row br of 64, 2 slots of 16B each)
    const int br = tid >> 2;
    const int bs = (tid & 3) * 2;
    const size_t woff = (size_t)(((br >> 4) << 10) + j0 + (br & 15)) * strideW + bs * 8;
    char* wdst = ldsB + br * 144 + bs * 16;

    for (int s = 0; s < nstages; ++s) {
        const int k0 = s << 6;                  // BK = 64
        const u16 *pAh, *pAl; int ka;
        if (k0 < K0) { pAh = A0h; pAl = A0l; ka = k0; }
        else         { pAh = A1h; pAl = A1l; ka = k0 - K0; }

        // prefetch A frags (global, overlap with B staging)
        bf16x8 a_h0 = *(const bf16x8*)(pAh + aoff + ka);
        bf16x8 a_l0 = *(const bf16x8*)(pAl + aoff + ka);
        bf16x8 a_h1 = *(const bf16x8*)(pAh + aoff + ka + 32);
        bf16x8 a_l1 = *(const bf16x8*)(pAl + aoff + ka + 32);

        uint4 gh0 = *(const uint4*)(Wh + woff + k0);
        uint4 gh1 = *(const uint4*)(Wh + woff + k0 + 8);
        uint4 gl0 = *(const uint4*)(Wl + woff + k0);
        uint4 gl1 = *(const uint4*)(Wl + woff + k0 + 8);

        __syncthreads();                        // prev iter's LDS reads done
        *(uint4*)(wdst)              = gh0;
        *(uint4*)(wdst + 16)         = gh1;
        *(uint4*)(wdst + 9216)       = gl0;
        *(uint4*)(wdst + 9216 + 16)  = gl1;
        __syncthreads();                        // stores visible

        #pragma unroll
        for (int kk = 0; kk < 2; ++kk) {
            bf16x8 ah = kk ? a_h1 : a_h0;
            bf16x8 al = kk ? a_l1 : a_l0;
            const int koffb = (kk * 4 + quad) * 16;
            #pragma unroll
            for (int g = 0; g < 4; ++g) {
                const char* bp = ldsB + (g * 16 + jloc) * 144 + koffb;
                bf16x8 bh = *(const bf16x8*)(bp);
                bf16x8 bl = *(const bf16x8*)(bp + 9216);
                acc[g] = __builtin_amdgcn_mfma_f32_16x16x32_bf16(ah, bh, acc[g], 0, 0, 0);
                acc[g] = __builtin_amdgcn_mfma_f32_16x16x32_bf16(ah, bl, acc[g], 0, 0, 0);
                acc[g] = __builtin_amdgcn_mfma_f32_16x16x32_bf16(al, bh, acc[g], 0, 0, 0);
            }
        }
    }

    // ---- epilogue: D row = quad*4+reg, col = lane&15 -> lane owns all 4 gates
    const int j = j0 + jloc;
    float bsv[4];
    #pragma unroll
    for (int g = 0; g < 4; ++g) bsv[g] = bias[(g << 10) + j];

    #pragma unroll
    for (int r = 0; r < 4; ++r) {
        int mloc = (wav << 4) + quad * 4 + r;
        int nb = m0 + mloc;
        float gv[4];
        #pragma unroll
        for (int g = 0; g < 4; ++g) {
            float v = acc[g][r] + bsv[g];
            if (USE_X) {
                float xd = 0.f;
                #pragma unroll
                for (int i = 0; i < INP; ++i) xd += ldsX[mloc][i] * ldsW6[g * 16 + jloc][i];
                v += xd;
            }
            gv[g] = v;
        }
        float I  = sigm(gv[0]);
        float F  = sigm(gv[1]);
        float Gv = tanh_fast(gv[2]);
        float O  = sigm(gv[3]);
        size_t ci = (size_t)nb * H + j;
        float cn = F * cbuf[ci] + I * Gv;
        cbuf[ci] = cn;
        float hn = O * tanh_fast(cn);
        u16 hh = f2bf(hn);
        u16 hl = f2bf(hn - bf2f(hh));
        size_t ho = (size_t)nb * 2048 + outcol + j;
        Hh[ho] = hh;
        Hl[ho] = hl;
    }
}

// ---- final linear on last h1 -------------------------------------------
__global__ __launch_bounds__(64)
void final_linear(const u16* __restrict__ Hh, const u16* __restrict__ Hl,
                  const float* __restrict__ linW, const float* __restrict__ linb,
                  float* __restrict__ out)
{
    int n = blockIdx.x;
    int lane = threadIdx.x;
    const u16* ph = Hh + (size_t)n * 2048 + 1024;
    const u16* pl = Hl + (size_t)n * 2048 + 1024;
    float s = 0.f;
    #pragma unroll
    for (int i = 0; i < 16; ++i) {
        int k = lane + i * 64;
        s += (bf2f(ph[k]) + bf2f(pl[k])) * linW[k];
    }
    #pragma unroll
    for (int m = 32; m >= 1; m >>= 1) s += __shfl_xor(s, m, 64);
    if (lane == 0) out[n] = s + linb[0];
}

extern "C" void kernel_launch(void* const* d_in, const int* in_sizes, int n_in,
                              void* d_out, int out_size, void* d_ws, size_t ws_size,
                              hipStream_t stream)
{
    (void)in_sizes; (void)n_in; (void)out_size; (void)ws_size;
    const float* seq  = (const float*)d_in[0];
    const float* Wih0 = (const float*)d_in[1];
    const float* Whh0 = (const float*)d_in[2];
    const float* bih0 = (const float*)d_in[3];
    const float* bhh0 = (const float*)d_in[4];
    const float* Wih1 = (const float*)d_in[5];
    const float* Whh1 = (const float*)d_in[6];
    const float* bih1 = (const float*)d_in[7];
    const float* bhh1 = (const float*)d_in[8];
    const float* linW = (const float*)d_in[9];
    const float* linb = (const float*)d_in[10];
    float* out = (float*)d_out;

    char* ws = (char*)d_ws;
    size_t off = 0;
    auto alloc = [&](size_t bytes) {
        char* p = ws + off;
        off += (bytes + 255) & ~(size_t)255;
        return p;
    };
    u16* W0h = (u16*)alloc((size_t)G4 * H * 2);
    u16* W0l = (u16*)alloc((size_t)G4 * H * 2);
    u16* W1h = (u16*)alloc((size_t)G4 * 2048 * 2);
    u16* W1l = (u16*)alloc((size_t)G4 * 2048 * 2);
    float* b0 = (float*)alloc((size_t)G4 * 4);
    float* b1 = (float*)alloc((size_t)G4 * 4);
    u16* Hh[2]; u16* Hl[2];
    Hh[0] = (u16*)alloc((size_t)NB * 2048 * 2);
    Hh[1] = (u16*)alloc((size_t)NB * 2048 * 2);
    Hl[0] = (u16*)alloc((size_t)NB * 2048 * 2);
    Hl[1] = (u16*)alloc((size_t)NB * 2048 * 2);
    float* c0 = (float*)alloc((size_t)NB * H * 4);
    float* c1 = (float*)alloc((size_t)NB * H * 4);

    pack_hi_lo<<<(G4 * H + 255) / 256, 256, 0, stream>>>(Whh0, W0h, W0l, G4 * H);
    pack_cat<<<(G4 * 2048) / 256, 256, 0, stream>>>(Wih1, Whh1, W1h, W1l);
    bias_sum<<<(G4 + 255) / 256, 256, 0, stream>>>(bih0, bhh0, b0, bih1, bhh1, b1);
    hipMemsetAsync(Hh[0], 0, (size_t)NB * 2048 * 2, stream);
    hipMemsetAsync(Hl[0], 0, (size_t)NB * 2048 * 2, stream);
    hipMemsetAsync(c0, 0, (size_t)NB * H * 4, stream);
    hipMemsetAsync(c1, 0, (size_t)NB * H * 4, stream);

    for (int t = 0; t < LSEQ; ++t) {
        int r = t & 1, w = 1 - r;
        // layer 0, step t: A = h0[t-1] (parity r, cols 0..1023); out h0[t] -> parity w
        lstm_step<true><<<256, 256, 0, stream>>>(
            Hh[r], Hl[r], Hh[r], Hl[r], 1024, 16,
            W0h, W0l, 1024, b0,
            seq + (size_t)t * NB * INP, Wih0,
            c0, Hh[w], Hl[w], 0);
        // layer 1, step t: A = [h0[t] (parity w, cols 0..) | h1[t-1] (parity r, cols 1024..)]
        lstm_step<false><<<256, 256, 0, stream>>>(
            Hh[w], Hl[w], Hh[r] + 1024, Hl[r] + 1024, 1024, 32,
            W1h, W1l, 2048, b1,
            nullptr, nullptr,
            c1, Hh[w], Hl[w], 1024);
    }
    // t=511 wrote parity w = 0
    final_linear<<<NB, 64, 0, stream>>>(Hh[0], Hl[0], linW, linb, out);
}